// Round 7
// baseline (767.447 us; speedup 1.0000x reference)
//
#include <hip/hip_runtime.h>

// ChunkedCrossAttention on MI355X (gfx950) — round 9 RESUBMIT (round-6 bench
// was an infra failure: "MI355X container failed twice"; kernel re-audited
// for OOB/LDS/API faults — none found; resubmitting unchanged).
// Changes vs round 8:
//  - proj moved from the 1-block/CU 256^2 8-phase engine to the m97 TLP
//    regime: 128^2 tile, 4 waves, single-buffered 32KB LDS, plain
//    stage->sync->compute->sync loop, ~112 VGPR -> ~4 blocks/CU co-resident.
//    Rationale: rounds 6/7/8 proved the 256^2 single-block schedule is
//    ceiling-locked at ~800 TF here (187/205/192us, MfmaUtil 32-35%) — with
//    1 block/CU every stall is exposed. m97/m114: sibling blocks cover
//    stalls; 874-912 TF with LESS scheduling.
//  - out8 -> out97 (same structure; the verified round-4 gemm_out).
//  - prep_k / cast_all / attn_kernel byte-identical to round 8.

#define DEV __device__ __forceinline__

typedef __bf16 bf16x8 __attribute__((ext_vector_type(8)));
typedef float f32x4 __attribute__((ext_vector_type(4)));

DEV unsigned short f2bf(float f) {
  union { float f; unsigned int u; } v; v.f = f;
  unsigned int u = v.u;
  unsigned int r = (u + 0x7FFFu + ((u >> 16) & 1u)) >> 16;  // RNE
  return (unsigned short)r;
}
DEV float bf2f(unsigned short h) {
  union { unsigned int u; float f; } v; v.u = ((unsigned int)h) << 16;
  return v.f;
}
DEV float bfelem(bf16x8 v, int i) {
  union { bf16x8 v; unsigned short u[8]; } t; t.v = v;
  return bf2f(t.u[i]);
}
// pack two fp32 -> two bf16 (RTZ): result = [bf16(lo), bf16(hi)]
DEV unsigned int pkbf(unsigned int hi, unsigned int lo) {
  return __builtin_amdgcn_perm(hi, lo, 0x07060302u);
}
// RNE pair pack
DEV unsigned int pk2(float lo, float hi) {
  return ((unsigned int)f2bf(hi) << 16) | f2bf(lo);
}

// async global->LDS, 16B per lane; LDS dest = wave-uniform base + lane*16
DEV void ldst16(const void* g, void* l) {
  __builtin_amdgcn_global_load_lds(
      (const __attribute__((address_space(1))) void*)g,
      (__attribute__((address_space(3))) void*)l, 16, 0, 0);
}

// ---------------------------------------------------------------------------
// prep: weight transpose+cast (+SCALE fold) via LDS tiles, zero rows 0..62
// per batch of out, rope cos/sin tables. One launch, grid 796.
// ---------------------------------------------------------------------------
__global__ __launch_bounds__(256) void prep_k(const float* __restrict__ Wq,
                                              const float* __restrict__ Wk,
                                              const float* __restrict__ Wv,
                                              const float* __restrict__ Wo,
                                              const float* __restrict__ qpe,
                                              const float* __restrict__ kpe,
                                              unsigned short* __restrict__ Wqt,
                                              unsigned short* __restrict__ Wkt,
                                              unsigned short* __restrict__ Wvt,
                                              unsigned short* __restrict__ Wot,
                                              float* __restrict__ ck, float* __restrict__ sk,
                                              float* __restrict__ cq, float* __restrict__ sq,
                                              float* __restrict__ out) {
  __shared__ float tl[64][65];
  int blk = blockIdx.x;
  int tid = threadIdx.x;
  if (blk < 512) {
    int mat = blk >> 7, loc = blk & 127;
    const float* W;
    unsigned short* Wt;
    int R, C;
    float scale = 1.0f;
    if (mat == 0)      { W = Wq; Wt = Wqt; R = 1024; C = 512; scale = 0.125f; }
    else if (mat == 1) { W = Wk; Wt = Wkt; R = 1024; C = 512; }
    else if (mat == 2) { W = Wv; Wt = Wvt; R = 1024; C = 512; }
    else               { W = Wo; Wt = Wot; R = 512;  C = 1024; }
    int nct = C >> 6;
    int rt = loc / nct, ct = loc % nct;
    int r0 = rt << 6, c0 = ct << 6;
    #pragma unroll
    for (int i = 0; i < 16; ++i) {
      int flat = i * 256 + tid;
      int rr = flat >> 6, cc = flat & 63;
      tl[rr][cc] = W[(size_t)(r0 + rr) * C + c0 + cc] * scale;
    }
    __syncthreads();
    #pragma unroll
    for (int i = 0; i < 16; ++i) {
      int flat = i * 256 + tid;
      int cc = flat >> 6, rr = flat & 63;
      Wt[(size_t)(c0 + cc) * R + r0 + rr] = f2bf(tl[rr][cc]);
    }
  } else if (blk < 764) {                  // zero rows 0..62 of each batch
    int r = blk - 512;
    int b = r / 63, rr = r % 63;
    float4 z = {0.f, 0.f, 0.f, 0.f};
    *(float4*)(out + (((size_t)(b * 4096 + rr)) << 10) + tid * 4) = z;
  } else {                                 // rope tables
    int t = (blk - 764) * 256 + tid;       // 0..8191
    float f = kpe[t];
    ck[t] = cosf(f);
    sk[t] = sinf(f);
    if (t < 64) {
      float g = qpe[63 * 64 + t];
      cq[t] = cosf(g);
      sq[t] = sinf(g);
    }
  }
}

// ---------------------------------------------------------------------------
// cast_all: ctx fp32 -> ctxb bf16 (flat, blocks [0,32768)), and x fp32 ->
// xb bf16 row-shifted by 63 + zero-pad (blocks [32768,40960)). RTZ pack.
// ---------------------------------------------------------------------------
__global__ __launch_bounds__(256) void cast_all(const float* __restrict__ ctx,
                                                const float* __restrict__ x,
                                                unsigned short* __restrict__ ctxb,
                                                unsigned short* __restrict__ xb) {
  int id = blockIdx.x;
  if (id < 32768) {
    size_t base = ((size_t)id * 256 + threadIdx.x) * 8;
    uint4 lo = *(const uint4*)(ctx + base);
    uint4 hi = *(const uint4*)(ctx + base + 4);
    uint4 pk;
    pk.x = pkbf(lo.y, lo.x);
    pk.y = pkbf(lo.w, lo.z);
    pk.z = pkbf(hi.y, hi.x);
    pk.w = pkbf(hi.w, hi.z);
    *(uint4*)(ctxb + base) = pk;
  } else {
    size_t e = ((size_t)(id - 32768) * 256 + threadIdx.x) * 8;
    int m = (int)(e >> 10), c = (int)(e & 1023);
    int b = m >> 12, t = m & 4095;
    uint4 pk = {0, 0, 0, 0};
    if (t <= 4032) {
      const float* s = x + (((size_t)(b << 12) + t + 63) << 10) + c;
      uint4 lo = *(const uint4*)s;
      uint4 hi = *(const uint4*)(s + 4);
      pk.x = pkbf(lo.y, lo.x);
      pk.y = pkbf(lo.w, lo.z);
      pk.z = pkbf(hi.y, hi.x);
      pk.w = pkbf(hi.w, hi.z);
    }
    *(uint4*)(xb + e) = pk;
  }
}

// ---------------------------------------------------------------------------
// m97-structure 128x128 GEMM core: 4 waves, As/Bs 8K shorts each (32KB),
// single-buffered: {8x ldst16} -> sync -> {2x k32: 8 ds_read + 16 MFMA} ->
// sync. Swizzled chunk layout phys_chunk(row,c) = row*8 + (c ^ (row&7)).
// TLP regime: ~112 VGPR + 32KB LDS -> ~4 blocks/CU; sibling blocks cover
// barrier/prologue stalls (m114).
// ---------------------------------------------------------------------------
DEV bf16x8 rdfrag(const unsigned short* b, int row, int c) {
  return *(const bf16x8*)((const char*)b + row * 128 + ((c ^ (row & 7)) << 4));
}
DEV bf16x8 rdfrag512(const unsigned short* b, int row, int c) {
  return *(const bf16x8*)((const char*)b + row * 512 + ((c ^ (row & 7)) << 4));
}

template <int KD>
DEV void kloop97(const unsigned short* __restrict__ A, const unsigned short* __restrict__ B,
                 unsigned short* sh, f32x4 (&acc)[4][4], int m0, int n0, int tid) {
  unsigned short* As = sh;
  unsigned short* Bs = sh + 8192;
  int w = tid >> 6, lane = tid & 63;
  int wm = (w & 1) * 64, wn = (w >> 1) * 64;
  int Lrow = lane >> 3, Lc = lane & 7;
  int srcC = Lc ^ (Lrow & 7);

  for (int k0 = 0; k0 < KD; k0 += 64) {
    #pragma unroll
    for (int q = 0; q < 4; ++q) {
      int t = w * 4 + q;
      ldst16(A + (size_t)(m0 + t * 8 + Lrow) * KD + (k0 + srcC * 8), (char*)As + t * 1024);
      ldst16(B + (size_t)(n0 + t * 8 + Lrow) * KD + (k0 + srcC * 8), (char*)Bs + t * 1024);
    }
    __syncthreads();
    #pragma unroll
    for (int k32 = 0; k32 < 2; ++k32) {
      int c = k32 * 4 + (lane >> 4);
      bf16x8 af[4], bfr[4];
      #pragma unroll
      for (int mt = 0; mt < 4; ++mt)
        af[mt] = rdfrag(As, wm + mt * 16 + (lane & 15), c);
      #pragma unroll
      for (int nt = 0; nt < 4; ++nt)
        bfr[nt] = rdfrag(Bs, wn + nt * 16 + (lane & 15), c);
      #pragma unroll
      for (int mt = 0; mt < 4; ++mt)
        #pragma unroll
        for (int nt = 0; nt < 4; ++nt)
          acc[mt][nt] = __builtin_amdgcn_mfma_f32_16x16x32_bf16(af[mt], bfr[nt], acc[mt][nt], 0, 0, 0);
    }
    __syncthreads();
  }
}

// ---------------------------------------------------------------------------
// proj97: merged Q/K/V projection on the m97 structure.
// Blocks [0,4096): K/V (A=ctxb, 512 m-panels x 4 n x {K,V});
// blocks [4096,4608): Q (A=xb, 128 m-panels x 4 n). K=1024.
// Epilogues (128-tile, round-4-verified): K->RoPE->kb; V->LDS-transpose->vtg;
// Q->RoPE(chunk-row0)->qbuf.
// ---------------------------------------------------------------------------
__global__ __launch_bounds__(256) void proj97(const unsigned short* __restrict__ ctxb,
                                              const unsigned short* __restrict__ xb,
                                              const unsigned short* __restrict__ Wkt,
                                              const unsigned short* __restrict__ Wvt,
                                              const unsigned short* __restrict__ Wqt,
                                              unsigned short* __restrict__ kb,
                                              unsigned short* __restrict__ vtg,
                                              unsigned short* __restrict__ qbuf,
                                              const float* __restrict__ ck,
                                              const float* __restrict__ sk,
                                              const float* __restrict__ cq,
                                              const float* __restrict__ sq) {
  __shared__ unsigned short sh[16384];  // 32 KiB
  int id = blockIdx.x;
  int mode, m0, n0;
  const unsigned short *A, *B;
  if (id < 4096) {                      // K/V
    int x = (id & 7) + 8 * (id >> 6);   // [0,512); 8 j-siblings same XCD slot
    int j = (id >> 3) & 7;
    int y = j & 3, z = j >> 2;
    mode = z;                           // 0 = K, 1 = V
    A = ctxb; B = z ? Wvt : Wkt;
    m0 = x * 128; n0 = y * 128;
  } else {                              // Q
    int t = id - 4096;                  // [0,512)
    int x = (t & 7) + 8 * (t >> 5);     // [0,128)
    int y = (t >> 3) & 3;
    mode = 2;
    A = xb; B = Wqt;
    m0 = x * 128; n0 = y * 128;
  }
  int tid = threadIdx.x, w = tid >> 6, lane = tid & 63;
  int wm = (w & 1) * 64, wn = (w >> 1) * 64;
  int ln15 = lane & 15, l4 = lane >> 4;

  f32x4 acc[4][4] = {};
  kloop97<1024>(A, B, sh, acc, m0, n0, tid);

  if (mode == 0) {  // K with RoPE: fi = (m&127)*64 + d
    #pragma unroll
    for (int mt = 0; mt < 4; ++mt)
      #pragma unroll
      for (int r = 0; r < 4; ++r) {
        int m = m0 + wm + mt * 16 + l4 * 4 + r;
        int fib = (m & 127) << 6;
        #pragma unroll
        for (int nt = 0; nt < 4; ++nt) {
          int n = n0 + wn + nt * 16 + ln15;
          int d = nt * 16 + ln15;
          float partner = acc[mt][nt ^ 2][r];
          float val = acc[mt][nt][r] * ck[fib + d] + (nt < 2 ? -partner : partner) * sk[fib + d];
          kb[(size_t)m * 512 + n] = f2bf(val);
        }
      }
  } else if (mode == 1) {  // V: transpose through LDS, store vtg[n][m]
    #pragma unroll
    for (int mt = 0; mt < 4; ++mt)
      #pragma unroll
      for (int nt = 0; nt < 4; ++nt)
        #pragma unroll
        for (int r = 0; r < 4; ++r) {
          int ml = wm + mt * 16 + l4 * 4 + r;
          int nl = wn + nt * 16 + ln15;
          int mc = ml >> 3, me = ml & 7;
          *(unsigned short*)((char*)sh + nl * 256 + ((mc ^ (nl & 15)) * 16) + me * 2) =
              f2bf(acc[mt][nt][r]);
        }
    __syncthreads();
    #pragma unroll
    for (int i = 0; i < 8; ++i) {
      int flat = i * 256 + tid;
      int nl = flat >> 4, mc = flat & 15;
      uint4 v = *(const uint4*)((const char*)sh + nl * 256 + ((mc ^ (nl & 15)) * 16));
      *(uint4*)(vtg + (size_t)(n0 + nl) * 65536 + m0 + mc * 8) = v;
    }
  } else {  // Q with RoPE on chunk-row 0
    #pragma unroll
    for (int mt = 0; mt < 4; ++mt)
      #pragma unroll
      for (int nt = 0; nt < 4; ++nt)
        #pragma unroll
        for (int r = 0; r < 4; ++r) {
          int m = m0 + wm + mt * 16 + l4 * 4 + r;
          int n = n0 + wn + nt * 16 + ln15;
          float val = acc[mt][nt][r];
          if ((m & 63) == 0) {
            int d = nt * 16 + ln15;
            float partner = acc[mt][nt ^ 2][r];
            val = val * cq[d] + (nt < 2 ? -partner : partner) * sq[d];
          }
          qbuf[(size_t)m * 512 + n] = f2bf(val);
        }
  }
}

// ---------------------------------------------------------------------------
// out97: out fp32 = obuf(16384x512) @ Wot^T(1024x512) + bias, row-shifted.
// 1024 blocks (128 x-panels x 8 y), K=512, m97 structure.
// ---------------------------------------------------------------------------
__global__ __launch_bounds__(256) void out97(const unsigned short* __restrict__ A,
                                             const unsigned short* __restrict__ B,
                                             const float* __restrict__ bias,
                                             float* __restrict__ out) {
  __shared__ unsigned short sh[16384];
  int id = blockIdx.x;
  int x = (id & 7) + 8 * (id >> 6), y = (id >> 3) & 7;
  int m0 = x * 128, n0 = y * 128;
  int tid = threadIdx.x, w = tid >> 6, lane = tid & 63;
  int wm = (w & 1) * 64, wn = (w >> 1) * 64;
  int ln15 = lane & 15, l4 = lane >> 4;

  f32x4 acc[4][4] = {};
  kloop97<512>(A, B, sh, acc, m0, n0, tid);

  #pragma unroll
  for (int mt = 0; mt < 4; ++mt)
    #pragma unroll
    for (int nt = 0; nt < 4; ++nt)
      #pragma unroll
      for (int r = 0; r < 4; ++r) {
        int m = m0 + wm + mt * 16 + l4 * 4 + r;
        int n = n0 + wn + nt * 16 + ln15;
        int b = m >> 12, t = m & 4095;
        if (t <= 4032)
          out[((size_t)((b << 12) + t + 63)) * 1024 + n] = acc[mt][nt][r] + bias[n];
      }
}

// ---------------------------------------------------------------------------
// Fused attention per (bc, h) — swapped-QK^T structure (unchanged).
// ---------------------------------------------------------------------------
__global__ __launch_bounds__(256) void attn_kernel(const unsigned short* __restrict__ qb,
                                                   const unsigned short* __restrict__ kb,
                                                   const unsigned short* __restrict__ vtg,
                                                   const float* __restrict__ nullk,
                                                   const float* __restrict__ nullv,
                                                   unsigned short* __restrict__ ob) {
  __shared__ unsigned short qs[64 * 64];    // 8 KB  [q][d]
  __shared__ unsigned short ks[256 * 64];   // 32 KB [j][d]; reused as ps[q][j]
  __shared__ unsigned short vs[64 * 256];   // 32 KB V^T [d][j]
  int id = blockIdx.x;
  int bc = (id & 7) + 8 * (id >> 6);
  int h = (id >> 3) & 7;
  int tid = threadIdx.x, w = tid >> 6, lane = tid & 63;
  int ln15 = lane & 15, l4 = lane >> 4;
  int Lrow = lane >> 3, srcC = (lane & 7) ^ (Lrow & 7);

  #pragma unroll
  for (int q8 = 0; q8 < 2; ++q8) {
    int t = w * 2 + q8;
    ldst16(qb + (size_t)(bc * 64 + t * 8 + Lrow) * 512 + h * 64 + srcC * 8, (char*)qs + t * 1024);
  }
  #pragma unroll
  for (int q8 = 0; q8 < 8; ++q8) {
    int t = w * 8 + q8;
    ldst16(kb + (size_t)(bc * 256 + t * 8 + Lrow) * 512 + h * 64 + srcC * 8, (char*)ks + t * 1024);
  }
  #pragma unroll
  for (int q8 = 0; q8 < 8; ++q8) {
    int t = w * 8 + q8;                 // 1KB region = V^T rows 2t, 2t+1
    int dd = t * 2 + (lane >> 5);
    int cl = (lane & 31) ^ (dd & 7);
    ldst16(vtg + (size_t)(h * 64 + dd) * 65536 + bc * 256 + cl * 8, (char*)vs + t * 1024);
  }
  __syncthreads();

  int q = w * 16 + ln15;   // this lane's q-row

  // null-key sim
  float ns = 0.f;
  {
    bf16x8 q0 = rdfrag(qs, q, l4 * 2);
    bf16x8 q1 = rdfrag(qs, q, l4 * 2 + 1);
    const float* nkp = nullk + h * 64 + l4 * 16;
    #pragma unroll
    for (int i = 0; i < 8; ++i) ns += bfelem(q0, i) * nkp[i];
    #pragma unroll
    for (int i = 0; i < 8; ++i) ns += bfelem(q1, i) * nkp[8 + i];
    ns += __shfl_xor(ns, 16);
    ns += __shfl_xor(ns, 32);
  }
  float rnull = __expf(ns);

  // QK^T swapped: acc[nt][r] = sim[j = nt*16 + l4*4 + r][q]
  f32x4 acc[16] = {};
  #pragma unroll
  for (int k32 = 0; k32 < 2; ++k32) {
    int c = k32 * 4 + l4;
    bf16x8 bq = rdfrag(qs, q, c);
    #pragma unroll
    for (int nt = 0; nt < 16; ++nt) {
      bf16x8 ak = rdfrag(ks, nt * 16 + ln15, c);
      acc[nt] = __builtin_amdgcn_mfma_f32_16x16x32_bf16(ak, bq, acc[nt], 0, 0, 0);
    }
  }

  // exp + per-q sum
  float s = 0.f;
  #pragma unroll
  for (int nt = 0; nt < 16; ++nt)
    #pragma unroll
    for (int r = 0; r < 4; ++r) {
      float p = __expf(acc[nt][r]);
      acc[nt][r] = p;
      s += p;
    }
  s += __shfl_xor(s, 16);
  s += __shfl_xor(s, 32);
  float rsum = s + rnull;

  __syncthreads();  // all waves done reading ks — safe to overlay ps

  // P -> ps[q][j] (over ks), b64 chunks
  #pragma unroll
  for (int nt = 0; nt < 16; ++nt) {
    unsigned int w0 = pk2(acc[nt][0], acc[nt][1]);
    unsigned int w1 = pk2(acc[nt][2], acc[nt][3]);
    int j = nt * 16 + l4 * 4;
    int cj = j >> 3;
    int off = (j & 7) * 2;
    uint2 v = {w0, w1};
    *(uint2*)((char*)ks + q * 512 + ((cj ^ (q & 7)) << 4) + off) = v;
  }
  // PV: o^T[d][q] = mfma(A = V^T rows d, B = P cols q)
  f32x4 oacc[4] = {};
  #pragma unroll
  for (int kk = 0; kk < 8; ++kk) {
    int c = kk * 4 + l4;
    bf16x8 bp = rdfrag512(ks, q, c);
    #pragma unroll
    for (int nt = 0; nt < 4; ++nt) {
      bf16x8 av = rdfrag512(vs, nt * 16 + ln15, c);
      oacc[nt] = __builtin_amdgcn_mfma_f32_16x16x32_bf16(av, bp, oacc[nt], 0, 0, 0);
    }
  }

  float inv = 1.0f / rsum;
  #pragma unroll
  for (int nt = 0; nt < 4; ++nt) {
    const float* nvp = nullv + h * 64 + nt * 16 + l4 * 4;
    float4 nv4 = *(const float4*)nvp;
    float o0 = (oacc[nt][0] + rnull * nv4.x) * inv;
    float o1 = (oacc[nt][1] + rnull * nv4.y) * inv;
    float o2 = (oacc[nt][2] + rnull * nv4.z) * inv;
    float o3 = (oacc[nt][3] + rnull * nv4.w) * inv;
    uint2 v = {pk2(o0, o1), pk2(o2, o3)};
    *(uint2*)(ob + ((size_t)(bc * 64 + q) * 8 + h) * 64 + nt * 16 + l4 * 4) = v;
  }
}

// ---------------------------------------------------------------------------
extern "C" void kernel_launch(void* const* d_in, const int* in_sizes, int n_in,
                              void* d_out, int out_size, void* d_ws, size_t ws_size,
                              hipStream_t stream) {
  const float* x = (const float*)d_in[0];
  const float* ctx = (const float*)d_in[1];
  const float* qpe = (const float*)d_in[2];
  const float* kpe = (const float*)d_in[3];
  const float* Wq = (const float*)d_in[4];
  const float* Wk = (const float*)d_in[5];
  const float* Wv = (const float*)d_in[6];
  const float* Wo = (const float*)d_in[7];
  const float* bo = (const float*)d_in[8];
  const float* nk = (const float*)d_in[9];
  const float* nv = (const float*)d_in[10];
  float* out = (float*)d_out;
  char* ws = (char*)d_ws;

  unsigned short* Wqt  = (unsigned short*)(ws + 0);          // 1 MB
  unsigned short* Wkt  = (unsigned short*)(ws + 1048576);    // 1 MB
  unsigned short* Wvt  = (unsigned short*)(ws + 2097152);    // 1 MB
  unsigned short* Wot  = (unsigned short*)(ws + 3145728);    // 1 MB
  float* cosk = (float*)(ws + 4194304);                      // 32 KB
  float* sink = (float*)(ws + 4227072);                      // 32 KB
  float* cosq = (float*)(ws + 4259840);                      // 256 B
  float* sinq = (float*)(ws + 4260096);                      // 256 B
  unsigned short* qb   = (unsigned short*)(ws + 8388608);    // 16 MB
  unsigned short* kb   = (unsigned short*)(ws + 25165824);   // 64 MB
  unsigned short* vtg  = (unsigned short*)(ws + 92274688);   // 64 MB (V^T [512][65536])
  unsigned short* obuf = (unsigned short*)(ws + 159383552);  // 16 MB
  unsigned short* xb   = (unsigned short*)(ws + 176160768);  // 32 MB (shifted x, bf16)
  unsigned short* ctxb = (unsigned short*)(ws + 209715200);  // 128 MB

  prep_k<<<796, 256, 0, stream>>>(Wq, Wk, Wv, Wo, qpe, kpe, Wqt, Wkt, Wvt, Wot,
                                  cosk, sink, cosq, sinq, out);

  cast_all<<<40960, 256, 0, stream>>>(ctx, x, ctxb, xb);

  // Q+K+V projections, m97 TLP structure (K/V: 4096 blocks, Q: 512)
  proj97<<<4608, 256, 0, stream>>>(ctxb, xb, Wkt, Wvt, Wqt, kb, vtg, qb,
                                   cosk, sink, cosq, sinq);

  attn_kernel<<<2048, 256, 0, stream>>>(qb, kb, vtg, nk, nv, obuf);

  // Output: (16384x512)@(512x1024) + bias, shifted rows
  out97<<<1024, 256, 0, stream>>>(obuf, Wot, bo, out);
}